// Round 1
// baseline (422.769 us; speedup 1.0000x reference)
//
#include <hip/hip_runtime.h>

// GRU, H=3, input (T,B,3) fp32, hidden (1,B,3).
// Layout: 4 lanes per batch chain (lane j in {0,1,2} owns hidden unit j,
// lane 3 mirrors lane 2 so quads stay full). 16 chains per wave64,
// 64-thread blocks, B/16 blocks -> 256 waves = 1 wave per CU at B=4096.
// The T-recurrence runs sequentially per chain; x-loads are prefetched
// PF steps ahead into a register ring to hide HBM latency.

#define PF 8
#define L2E 1.4426950408889634f

__device__ __forceinline__ float fast_sigmoid(float v) {
    // 1 / (1 + 2^(-x*log2e))
    return __builtin_amdgcn_rcpf(1.0f + __builtin_amdgcn_exp2f(-L2E * v));
}

__device__ __forceinline__ float fast_tanh(float v) {
    // 1 - 2/(2^(2x*log2e) + 1)
    float e = __builtin_amdgcn_exp2f((2.0f * L2E) * v);
    return 1.0f - 2.0f * __builtin_amdgcn_rcpf(e + 1.0f);
}

__global__ __launch_bounds__(64, 1)
void gru_seq_kernel(const float* __restrict__ x,    // (T,B,3)
                    const float* __restrict__ h0,   // (B,3)
                    const float* __restrict__ Wih,  // (9,3) row-major
                    const float* __restrict__ Whh,  // (9,3)
                    const float* __restrict__ bih,  // (9)
                    const float* __restrict__ bhh,  // (9)
                    float* __restrict__ out,        // (T,B,3) then (B,3)
                    int T, int B)
{
    const int lane  = threadIdx.x & 63;
    const int q     = lane & 3;
    const int j     = (q < 3) ? q : 2;           // lane 3 duplicates unit 2
    const int chain = blockIdx.x * 16 + (lane >> 2);
    if (chain >= B) return;

    // Per-lane weight rows: r -> row j, z -> row 3+j, n -> row 6+j.
    const float wir0 = Wih[(0 + j) * 3 + 0], wir1 = Wih[(0 + j) * 3 + 1], wir2 = Wih[(0 + j) * 3 + 2];
    const float wiz0 = Wih[(3 + j) * 3 + 0], wiz1 = Wih[(3 + j) * 3 + 1], wiz2 = Wih[(3 + j) * 3 + 2];
    const float win0 = Wih[(6 + j) * 3 + 0], win1 = Wih[(6 + j) * 3 + 1], win2 = Wih[(6 + j) * 3 + 2];
    const float whr0 = Whh[(0 + j) * 3 + 0], whr1 = Whh[(0 + j) * 3 + 1], whr2 = Whh[(0 + j) * 3 + 2];
    const float whz0 = Whh[(3 + j) * 3 + 0], whz1 = Whh[(3 + j) * 3 + 1], whz2 = Whh[(3 + j) * 3 + 2];
    const float whn0 = Whh[(6 + j) * 3 + 0], whn1 = Whh[(6 + j) * 3 + 1], whn2 = Whh[(6 + j) * 3 + 2];
    // r,z biases fold (b_ih + b_hh); n keeps them split (r gates b_hh side).
    const float br  = bih[0 + j] + bhh[0 + j];
    const float bz  = bih[3 + j] + bhh[3 + j];
    const float bni = bih[6 + j];
    const float bnh = bhh[6 + j];

    // Initial hidden state.
    float hv0 = h0[chain * 3 + 0];
    float hv1 = h0[chain * 3 + 1];
    float hv2 = h0[chain * 3 + 2];
    float myh = (j == 0) ? hv0 : ((j == 1) ? hv1 : hv2);

    const int lb      = lane & ~3;        // quad base lane for shuffles
    const int stride  = B * 3;
    const int cb      = chain * 3;
    const int end_off  = cb + T * stride; // first out-of-range x offset
    const int last_off = cb + (T - 1) * stride;

    // Prefetch ring: PF steps of x in registers.
    float xb[PF][3];
#pragma unroll
    for (int i = 0; i < PF; ++i) {
        int tt = (i < T) ? i : (T - 1);
        const float* p = x + (size_t)(cb + tt * stride);
        xb[i][0] = p[0]; xb[i][1] = p[1]; xb[i][2] = p[2];
    }

    int pf_off = cb + PF * stride;  // next offset to prefetch
    int o_off  = cb + j;            // store offset for t=0

    auto step = [&](int u) {
        // Consume current x, immediately refill slot with x[t+PF].
        float x0 = xb[u][0], x1 = xb[u][1], x2 = xb[u][2];
        int lo = (pf_off < end_off) ? pf_off : last_off;  // clamp tail (redundant re-read)
        const float* p = x + (size_t)lo;
        xb[u][0] = p[0]; xb[u][1] = p[1]; xb[u][2] = p[2];
        pf_off += stride;

        float ar  = wir0 * x0 + wir1 * x1 + wir2 * x2
                  + whr0 * hv0 + whr1 * hv1 + whr2 * hv2 + br;
        float az  = wiz0 * x0 + wiz1 * x1 + wiz2 * x2
                  + whz0 * hv0 + whz1 * hv1 + whz2 * hv2 + bz;
        float ani = win0 * x0 + win1 * x1 + win2 * x2 + bni;
        float anh = whn0 * hv0 + whn1 * hv1 + whn2 * hv2 + bnh;

        float r = fast_sigmoid(ar);
        float z = fast_sigmoid(az);
        float n = fast_tanh(ani + r * anh);
        myh = z * (myh - n) + n;    // (1-z)*n + z*h

        out[o_off] = myh;           // lane 3 double-writes lane 2's value (same addr, same data)
        o_off += stride;

        // Broadcast the new h triple within the quad for the next step.
        hv0 = __shfl(myh, lb + 0, 64);
        hv1 = __shfl(myh, lb + 1, 64);
        hv2 = __shfl(myh, lb + 2, 64);
    };

    const int tmain = (T / PF) * PF;
    for (int t = 0; t < tmain; t += PF) {
#pragma unroll
        for (int u = 0; u < PF; ++u) step(u);
    }
    for (int t = tmain; t < T; ++t) step(t - tmain);

    // h_last tail: d_out = [output (T*B*3) | h_last (B*3)]; o_off == T*stride + cb + j.
    out[o_off] = myh;
}

extern "C" void kernel_launch(void* const* d_in, const int* in_sizes, int n_in,
                              void* d_out, int out_size, void* d_ws, size_t ws_size,
                              hipStream_t stream) {
    const float* x   = (const float*)d_in[0];
    const float* h0  = (const float*)d_in[1];
    const float* Wih = (const float*)d_in[2];
    const float* Whh = (const float*)d_in[3];
    const float* bih = (const float*)d_in[4];
    const float* bhh = (const float*)d_in[5];
    float* out = (float*)d_out;

    const int B = in_sizes[1] / 3;              // hidden is (1,B,3)
    const int T = in_sizes[0] / in_sizes[1];    // input is (T,B,3)

    const int grid = (B + 15) / 16;             // 16 chains per 64-thread block
    gru_seq_kernel<<<grid, 64, 0, stream>>>(x, h0, Wih, Whh, bih, bhh, out, T, B);
}

// Round 2
// 383.887 us; speedup vs baseline: 1.1013x; 1.1013x over previous
//
#include <hip/hip_runtime.h>

// GRU, H=3, input (T,B,3) fp32, hidden (1,B,3).
// Layout: 4 lanes per batch chain (lane j in {0,1,2} owns hidden unit j,
// lane 3 mirrors lane 2 so quads stay full). 16 chains per wave64,
// 64-thread blocks, B/16 blocks -> 256 waves = 1 wave per CU at B=4096.
//
// R2 change: quad-broadcast of h via DPP quad_perm (pure VALU, ~2-4 cyc)
// instead of __shfl (ds_bpermute + lgkmcnt drain on the critical path).

#define PF 8
#define L2E 1.4426950408889634f

__device__ __forceinline__ float fast_sigmoid(float v) {
    // 1 / (1 + 2^(-x*log2e))
    return __builtin_amdgcn_rcpf(1.0f + __builtin_amdgcn_exp2f(-L2E * v));
}

__device__ __forceinline__ float fast_tanh(float v) {
    // 1 - 2/(2^(2x*log2e) + 1)
    float e = __builtin_amdgcn_exp2f((2.0f * L2E) * v);
    return 1.0f - 2.0f * __builtin_amdgcn_rcpf(e + 1.0f);
}

// Broadcast lane (quad_base + K) to all 4 lanes of the quad. CTRL is the
// 8-bit quad_perm selector: [K,K,K,K] -> K*0b01010101.
template <int CTRL>
__device__ __forceinline__ float quad_bcast(float v) {
    int i = __float_as_int(v);
    int r = __builtin_amdgcn_update_dpp(i, i, CTRL, 0xF, 0xF, true);
    return __int_as_float(r);
}

__global__ __launch_bounds__(64, 1)
void gru_seq_kernel(const float* __restrict__ x,    // (T,B,3)
                    const float* __restrict__ h0,   // (B,3)
                    const float* __restrict__ Wih,  // (9,3) row-major
                    const float* __restrict__ Whh,  // (9,3)
                    const float* __restrict__ bih,  // (9)
                    const float* __restrict__ bhh,  // (9)
                    float* __restrict__ out,        // (T,B,3) then (B,3)
                    int T, int B)
{
    const int lane  = threadIdx.x & 63;
    const int q     = lane & 3;
    const int j     = (q < 3) ? q : 2;           // lane 3 duplicates unit 2
    const int chain = blockIdx.x * 16 + (lane >> 2);
    if (chain >= B) return;

    // Per-lane weight rows: r -> row j, z -> row 3+j, n -> row 6+j.
    const float wir0 = Wih[(0 + j) * 3 + 0], wir1 = Wih[(0 + j) * 3 + 1], wir2 = Wih[(0 + j) * 3 + 2];
    const float wiz0 = Wih[(3 + j) * 3 + 0], wiz1 = Wih[(3 + j) * 3 + 1], wiz2 = Wih[(3 + j) * 3 + 2];
    const float win0 = Wih[(6 + j) * 3 + 0], win1 = Wih[(6 + j) * 3 + 1], win2 = Wih[(6 + j) * 3 + 2];
    const float whr0 = Whh[(0 + j) * 3 + 0], whr1 = Whh[(0 + j) * 3 + 1], whr2 = Whh[(0 + j) * 3 + 2];
    const float whz0 = Whh[(3 + j) * 3 + 0], whz1 = Whh[(3 + j) * 3 + 1], whz2 = Whh[(3 + j) * 3 + 2];
    const float whn0 = Whh[(6 + j) * 3 + 0], whn1 = Whh[(6 + j) * 3 + 1], whn2 = Whh[(6 + j) * 3 + 2];
    // r,z biases fold (b_ih + b_hh); n keeps them split (r gates b_hh side).
    const float br  = bih[0 + j] + bhh[0 + j];
    const float bz  = bih[3 + j] + bhh[3 + j];
    const float bni = bih[6 + j];
    const float bnh = bhh[6 + j];

    // Initial hidden state.
    float hv0 = h0[chain * 3 + 0];
    float hv1 = h0[chain * 3 + 1];
    float hv2 = h0[chain * 3 + 2];
    float myh = (j == 0) ? hv0 : ((j == 1) ? hv1 : hv2);

    const int stride  = B * 3;
    const int cb      = chain * 3;
    const int end_off  = cb + T * stride; // first out-of-range x offset
    const int last_off = cb + (T - 1) * stride;

    // Prefetch ring: PF steps of x in registers.
    float xb[PF][3];
#pragma unroll
    for (int i = 0; i < PF; ++i) {
        int tt = (i < T) ? i : (T - 1);
        const float* p = x + (size_t)(cb + tt * stride);
        xb[i][0] = p[0]; xb[i][1] = p[1]; xb[i][2] = p[2];
    }

    int pf_off = cb + PF * stride;  // next offset to prefetch
    int o_off  = cb + j;            // store offset for t=0

    auto step = [&](int u) {
        // Consume current x, immediately refill slot with x[t+PF].
        float x0 = xb[u][0], x1 = xb[u][1], x2 = xb[u][2];
        int lo = (pf_off < end_off) ? pf_off : last_off;  // clamp tail (redundant re-read)
        const float* p = x + (size_t)lo;
        xb[u][0] = p[0]; xb[u][1] = p[1]; xb[u][2] = p[2];
        pf_off += stride;

        float ar  = wir0 * x0 + wir1 * x1 + wir2 * x2
                  + whr0 * hv0 + whr1 * hv1 + whr2 * hv2 + br;
        float az  = wiz0 * x0 + wiz1 * x1 + wiz2 * x2
                  + whz0 * hv0 + whz1 * hv1 + whz2 * hv2 + bz;
        float ani = win0 * x0 + win1 * x1 + win2 * x2 + bni;
        float anh = whn0 * hv0 + whn1 * hv1 + whn2 * hv2 + bnh;

        float r = fast_sigmoid(ar);
        float z = fast_sigmoid(az);
        float n = fast_tanh(ani + r * anh);
        myh = z * (myh - n) + n;    // (1-z)*n + z*h

        out[o_off] = myh;           // lane 3 double-writes lane 2's value (same addr, same data)
        o_off += stride;

        // Broadcast the new h triple within the quad for the next step (DPP, VALU-only).
        hv0 = quad_bcast<0x00>(myh);   // quad_perm [0,0,0,0]
        hv1 = quad_bcast<0x55>(myh);   // quad_perm [1,1,1,1]
        hv2 = quad_bcast<0xAA>(myh);   // quad_perm [2,2,2,2]
    };

    const int tmain = (T / PF) * PF;
    for (int t = 0; t < tmain; t += PF) {
#pragma unroll
        for (int u = 0; u < PF; ++u) step(u);
    }
    for (int t = tmain; t < T; ++t) step(t - tmain);

    // h_last tail: d_out = [output (T*B*3) | h_last (B*3)]; o_off == T*stride + cb + j.
    out[o_off] = myh;
}

extern "C" void kernel_launch(void* const* d_in, const int* in_sizes, int n_in,
                              void* d_out, int out_size, void* d_ws, size_t ws_size,
                              hipStream_t stream) {
    const float* x   = (const float*)d_in[0];
    const float* h0  = (const float*)d_in[1];
    const float* Wih = (const float*)d_in[2];
    const float* Whh = (const float*)d_in[3];
    const float* bih = (const float*)d_in[4];
    const float* bhh = (const float*)d_in[5];
    float* out = (float*)d_out;

    const int B = in_sizes[1] / 3;              // hidden is (1,B,3)
    const int T = in_sizes[0] / in_sizes[1];    // input is (T,B,3)

    const int grid = (B + 15) / 16;             // 16 chains per 64-thread block
    gru_seq_kernel<<<grid, 64, 0, stream>>>(x, h0, Wih, Whh, bih, bhh, out, T, B);
}